// Round 2
// baseline (553.694 us; speedup 1.0000x reference)
//
#include <hip/hip_runtime.h>
#include <hip/hip_bf16.h>

#define EPS_Z 1e-4f

typedef __attribute__((ext_vector_type(8))) short bf16x8;
typedef __attribute__((ext_vector_type(4))) float f32x4;

__device__ __forceinline__ float b2f(short s) {
    union { unsigned u; float f; } cv;
    cv.u = ((unsigned)(unsigned short)s) << 16;
    return cv.f;
}

__device__ __forceinline__ void gld_lds16(const __hip_bfloat16* g, __hip_bfloat16* l) {
    __builtin_amdgcn_global_load_lds(
        (__attribute__((address_space(1))) void*)(g),
        (__attribute__((address_space(3))) void*)(l),
        16, 0, 0);
}

// fp32 -> bf16 (RNE), 4 elems/thread
__global__ __launch_bounds__(256)
void cvt_f32_bf16(const float* __restrict__ in, __hip_bfloat16* __restrict__ out, int n4)
{
    int i = blockIdx.x * 256 + threadIdx.x;
    if (i >= n4) return;
    float4 v = ((const float4*)in)[i];
    union { short4 s; __hip_bfloat16 h[4]; } o;
    o.h[0] = __float2bfloat16(v.x);
    o.h[1] = __float2bfloat16(v.y);
    o.h[2] = __float2bfloat16(v.z);
    o.h[3] = __float2bfloat16(v.w);
    ((short4*)out)[i] = o.s;
}

// C[M,N] = A[M,K] @ B[N,K]^T ; A,B bf16, fp32 accumulate.
// MODE 1: relu on cols < 1536 (q,k of qkv), C bf16. MODE 2: += fp32 bias, C fp32.
template<int MODE, typename CT>
__global__ __launch_bounds__(256, 2)
void gemm_bt(const __hip_bfloat16* __restrict__ A,
             const __hip_bfloat16* __restrict__ B,
             CT* __restrict__ C,
             const float* __restrict__ bias,
             int K, int N)
{
    __shared__ __align__(16) __hip_bfloat16 As[128 * 64];
    __shared__ __align__(16) __hip_bfloat16 Bs[128 * 64];
    const int tid = threadIdx.x;
    const int w = tid >> 6;
    const int l = tid & 63;
    const int wr = (w >> 1) * 64;   // wave's 64-row sub-tile
    const int wc = (w & 1) * 64;    // wave's 64-col sub-tile
    const int l15 = l & 15;
    const int lq = l >> 4;

    f32x4 acc[4][4] = {};

    const int srow8 = l >> 3;           // row within 8-row chunk
    const int scol = (l & 7) << 3;      // col (elems) within 64-wide tile row

    const __hip_bfloat16* Ab = A + (size_t)blockIdx.x * 128 * K;
    const __hip_bfloat16* Bb = B + (size_t)blockIdx.y * 128 * K;

    for (int k0 = 0; k0 < K; k0 += 64) {
        __syncthreads();
        #pragma unroll
        for (int i = 0; i < 4; ++i) {
            const int chunk = w * 4 + i;         // 16 chunks of 1024B per tile
            const int row = chunk * 8 + srow8;   // 0..127
            gld_lds16(Ab + (size_t)row * K + (k0 + scol), As + chunk * 512);
            gld_lds16(Bb + (size_t)row * K + (k0 + scol), Bs + chunk * 512);
        }
        __syncthreads();   // compiler emits vmcnt(0) drain before barrier
        #pragma unroll
        for (int kk = 0; kk < 64; kk += 32) {
            const int koff = kk + lq * 8;
            bf16x8 a[4], b[4];
            #pragma unroll
            for (int i = 0; i < 4; ++i)
                a[i] = *(const bf16x8*)(As + (wr + i * 16 + l15) * 64 + koff);
            #pragma unroll
            for (int j = 0; j < 4; ++j)
                b[j] = *(const bf16x8*)(Bs + (wc + j * 16 + l15) * 64 + koff);
            #pragma unroll
            for (int i = 0; i < 4; ++i)
                #pragma unroll
                for (int j = 0; j < 4; ++j)
                    acc[i][j] = __builtin_amdgcn_mfma_f32_16x16x32_bf16(a[i], b[j], acc[i][j], 0, 0, 0);
        }
    }

    // C/D layout: col = lane&15, row = (lane>>4)*4 + r  [m89/m91 verified]
    const int crow0 = blockIdx.x * 128 + wr + lq * 4;
    const int ccol0 = blockIdx.y * 128 + wc + l15;
    #pragma unroll
    for (int i = 0; i < 4; ++i) {
        #pragma unroll
        for (int j = 0; j < 4; ++j) {
            const int gc = ccol0 + j * 16;
            const float badd = (MODE == 2) ? bias[gc] : 0.0f;
            #pragma unroll
            for (int r = 0; r < 4; ++r) {
                const int gr = crow0 + i * 16 + r;
                float v = acc[i][j][r];
                if (MODE == 1 && gc < 1536) v = fmaxf(v, 0.0f);
                if (MODE == 2) v += badd;
                if (MODE == 1)
                    ((__hip_bfloat16*)C)[(size_t)gr * N + gc] = __float2bfloat16(v);
                else
                    ((float*)C)[(size_t)gr * N + gc] = v;
            }
        }
    }
}

// kv[b,h,e,d] = sum_s k[s,e]*v[s,d]; k_sum[b,h,e] = sum_s k[s,e].
// Split-K x7 across blocks, fp32 atomics. qkv row layout: [q 768 | k 768 | v 768].
__global__ __launch_bounds__(256)
void kv_ksum_kernel(const __hip_bfloat16* __restrict__ qkv,
                    float* __restrict__ kvg, float* __restrict__ ksumg)
{
    const int SPLIT = 7, CH = 3136 / 7;   // 448, divisible by 16
    const int bh = blockIdx.x / SPLIT;
    const int ck = blockIdx.x % SPLIT;
    const int b = bh / 12, h = bh % 12;
    const int tid = threadIdx.x;
    const int e = tid >> 2;
    const int d0 = (tid & 3) << 4;

    __shared__ __align__(16) float ks[16][64];
    __shared__ __align__(16) float vs[16][64];

    float acc[16];
    #pragma unroll
    for (int d = 0; d < 16; ++d) acc[d] = 0.0f;
    float ksacc = 0.0f;

    const int half = tid >> 7;            // 0: stage k, 1: stage v
    const int lr = (tid >> 3) & 15;
    const int lc = (tid & 7) << 3;
    const size_t base = (size_t)b * 3136 * 2304 + (half ? 1536 : 768) + h * 64 + lc;

    for (int s0 = ck * CH; s0 < (ck + 1) * CH; s0 += 16) {
        __syncthreads();
        bf16x8 t = *(const bf16x8*)(qkv + base + (size_t)(s0 + lr) * 2304);
        float* dst = half ? &vs[lr][lc] : &ks[lr][lc];
        #pragma unroll
        for (int q = 0; q < 8; ++q) dst[q] = b2f(t[q]);
        __syncthreads();
        #pragma unroll
        for (int ss = 0; ss < 16; ++ss) {
            const float kval = ks[ss][e];
            if ((tid & 3) == 0) ksacc += kval;
            #pragma unroll
            for (int d = 0; d < 16; ++d)
                acc[d] += kval * vs[ss][d0 + d];
        }
    }
    float* kvdst = kvg + ((size_t)bh << 12) + (e << 6) + d0;
    #pragma unroll
    for (int d = 0; d < 16; ++d) atomicAdd(kvdst + d, acc[d]);
    if ((tid & 3) == 0) atomicAdd(ksumg + (bh << 6) + e, ksacc);
}

// att[m, h*64+d] = (sum_e q[m,e]*kv[e,d]) / (q[m,:].k_sum + eps)
__global__ __launch_bounds__(256)
void attn_out_kernel(const __hip_bfloat16* __restrict__ qkv,
                     const float* __restrict__ kvg,
                     const float* __restrict__ ksumg,
                     __hip_bfloat16* __restrict__ att)
{
    const int bh = blockIdx.x / 49;
    const int rc = blockIdx.x % 49;
    const int b = bh / 12, h = bh % 12;
    __shared__ __align__(16) float kvs[4096];
    __shared__ float kss[64];
    for (int i = threadIdx.x; i < 4096; i += 256) kvs[i] = kvg[((size_t)bh << 12) + i];
    if (threadIdx.x < 64) kss[threadIdx.x] = ksumg[(bh << 6) + threadIdx.x];
    __syncthreads();

    const int r = threadIdx.x >> 2;
    const int d0 = (threadIdx.x & 3) << 4;
    const size_t m = (size_t)b * 3136 + rc * 64 + r;
    const __hip_bfloat16* qrow = qkv + m * 2304 + h * 64;   // q already relu'd

    float q[64];
    #pragma unroll
    for (int i = 0; i < 8; ++i) {
        bf16x8 t = *(const bf16x8*)(qrow + i * 8);
        #pragma unroll
        for (int j = 0; j < 8; ++j) q[i * 8 + j] = b2f(t[j]);
    }
    float zden = EPS_Z;
    #pragma unroll
    for (int e = 0; e < 64; ++e) zden += q[e] * kss[e];
    const float z = 1.0f / zden;

    float acc[16];
    #pragma unroll
    for (int d = 0; d < 16; ++d) acc[d] = 0.0f;
    #pragma unroll
    for (int e = 0; e < 64; ++e) {
        const float qe = q[e];
        #pragma unroll
        for (int d = 0; d < 16; ++d)
            acc[d] += qe * kvs[(e << 6) + d0 + d];
    }
    __hip_bfloat16* dst = att + m * 768 + h * 64 + d0;
    #pragma unroll
    for (int d = 0; d < 16; ++d) dst[d] = __float2bfloat16(acc[d] * z);
}

extern "C" void kernel_launch(void* const* d_in, const int* in_sizes, int n_in,
                              void* d_out, int out_size, void* d_ws, size_t ws_size,
                              hipStream_t stream)
{
    const float* x      = (const float*)d_in[0];   // [128*196, 768]
    const float* W_qkv  = (const float*)d_in[1];   // [2304, 768]
    const float* W_proj = (const float*)d_in[2];   // [768, 768]
    const float* b_proj = (const float*)d_in[3];   // [768]
    float* out = (float*)d_out;

    const int M = 25088, K = 768, N1 = 2304, N2 = 768;

    // workspace layout (bf16 elems unless noted); att aliases xb (x consumed by gemm1)
    __hip_bfloat16* qkv = (__hip_bfloat16*)d_ws;            // M*N1   = 57,802,752
    __hip_bfloat16* xb  = qkv + (size_t)M * N1;             // M*K    = 19,267,584
    __hip_bfloat16* wqb = xb + (size_t)M * K;               // N1*K   =  1,769,472
    __hip_bfloat16* wpb = wqb + (size_t)N1 * K;             // N2*K   =    589,824
    float* kvg  = (float*)(wpb + (size_t)N2 * K);           // 96*4096 fp32
    float* ksum = kvg + 96 * 4096;                          // 96*64 fp32
    __hip_bfloat16* att = xb;                               // alias: M*N2 <= M*K

    hipMemsetAsync(kvg, 0, (size_t)(96 * 4096 + 96 * 64) * sizeof(float), stream);

    cvt_f32_bf16<<<(M * K / 4 + 255) / 256, 256, 0, stream>>>(x, xb, M * K / 4);
    cvt_f32_bf16<<<(N1 * K / 4 + 255) / 256, 256, 0, stream>>>(W_qkv, wqb, N1 * K / 4);
    cvt_f32_bf16<<<(N2 * K / 4 + 255) / 256, 256, 0, stream>>>(W_proj, wpb, N2 * K / 4);

    gemm_bt<1, __hip_bfloat16><<<dim3(M / 128, N1 / 128), 256, 0, stream>>>(xb, wqb, qkv, nullptr, K, N1);
    kv_ksum_kernel<<<96 * 7, 256, 0, stream>>>(qkv, kvg, ksum);
    attn_out_kernel<<<96 * 49, 256, 0, stream>>>(qkv, kvg, ksum, att);
    gemm_bt<2, float><<<dim3(M / 128, N2 / 128), 256, 0, stream>>>(att, wpb, out, b_proj, K, N2);
}

// Round 3
// 382.079 us; speedup vs baseline: 1.4492x; 1.4492x over previous
//
#include <hip/hip_runtime.h>
#include <hip/hip_bf16.h>

#define EPS_Z 1e-4f

typedef __attribute__((ext_vector_type(8))) short bf16x8;
typedef __attribute__((ext_vector_type(4))) float f32x4;

__device__ __forceinline__ float b2f(short s) {
    union { unsigned u; float f; } cv;
    cv.u = ((unsigned)(unsigned short)s) << 16;
    return cv.f;
}

__device__ __forceinline__ void gld_lds16(const __hip_bfloat16* g, __hip_bfloat16* l) {
    __builtin_amdgcn_global_load_lds(
        (__attribute__((address_space(1))) void*)(g),
        (__attribute__((address_space(3))) void*)(l),
        16, 0, 0);
}

// fp32 -> bf16 (RNE), 4 elems/thread
__global__ __launch_bounds__(256)
void cvt_f32_bf16(const float* __restrict__ in, __hip_bfloat16* __restrict__ out, int n4)
{
    int i = blockIdx.x * 256 + threadIdx.x;
    if (i >= n4) return;
    float4 v = ((const float4*)in)[i];
    union { short4 s; __hip_bfloat16 h[4]; } o;
    o.h[0] = __float2bfloat16(v.x);
    o.h[1] = __float2bfloat16(v.y);
    o.h[2] = __float2bfloat16(v.z);
    o.h[3] = __float2bfloat16(v.w);
    ((short4*)out)[i] = o.s;
}

// C[M,N] = A[M,K] @ B[N,K]^T ; A,B bf16, fp32 accumulate.
// MODE 1: relu on cols < 1536 (q,k of qkv), C bf16. MODE 2: += fp32 bias, C fp32.
template<int MODE, typename CT>
__global__ __launch_bounds__(256, 2)
void gemm_bt(const __hip_bfloat16* __restrict__ A,
             const __hip_bfloat16* __restrict__ B,
             CT* __restrict__ C,
             const float* __restrict__ bias,
             int K, int N)
{
    __shared__ __align__(16) __hip_bfloat16 As[128 * 64];
    __shared__ __align__(16) __hip_bfloat16 Bs[128 * 64];
    const int tid = threadIdx.x;
    const int w = tid >> 6;
    const int l = tid & 63;
    const int wr = (w >> 1) * 64;
    const int wc = (w & 1) * 64;
    const int l15 = l & 15;
    const int lq = l >> 4;

    f32x4 acc[4][4] = {};

    const int srow8 = l >> 3;
    const int scol = (l & 7) << 3;

    const __hip_bfloat16* Ab = A + (size_t)blockIdx.x * 128 * K;
    const __hip_bfloat16* Bb = B + (size_t)blockIdx.y * 128 * K;

    for (int k0 = 0; k0 < K; k0 += 64) {
        __syncthreads();
        #pragma unroll
        for (int i = 0; i < 4; ++i) {
            const int chunk = w * 4 + i;
            const int row = chunk * 8 + srow8;
            gld_lds16(Ab + (size_t)row * K + (k0 + scol), As + chunk * 512);
            gld_lds16(Bb + (size_t)row * K + (k0 + scol), Bs + chunk * 512);
        }
        __syncthreads();
        #pragma unroll
        for (int kk = 0; kk < 64; kk += 32) {
            const int koff = kk + lq * 8;
            bf16x8 a[4], b[4];
            #pragma unroll
            for (int i = 0; i < 4; ++i)
                a[i] = *(const bf16x8*)(As + (wr + i * 16 + l15) * 64 + koff);
            #pragma unroll
            for (int j = 0; j < 4; ++j)
                b[j] = *(const bf16x8*)(Bs + (wc + j * 16 + l15) * 64 + koff);
            #pragma unroll
            for (int i = 0; i < 4; ++i)
                #pragma unroll
                for (int j = 0; j < 4; ++j)
                    acc[i][j] = __builtin_amdgcn_mfma_f32_16x16x32_bf16(a[i], b[j], acc[i][j], 0, 0, 0);
        }
    }

    const int crow0 = blockIdx.x * 128 + wr + lq * 4;
    const int ccol0 = blockIdx.y * 128 + wc + l15;
    #pragma unroll
    for (int i = 0; i < 4; ++i) {
        #pragma unroll
        for (int j = 0; j < 4; ++j) {
            const int gc = ccol0 + j * 16;
            const float badd = (MODE == 2) ? bias[gc] : 0.0f;
            #pragma unroll
            for (int r = 0; r < 4; ++r) {
                const int gr = crow0 + i * 16 + r;
                float v = acc[i][j][r];
                if (MODE == 1 && gc < 1536) v = fmaxf(v, 0.0f);
                if (MODE == 2) v += badd;
                if (MODE == 1)
                    ((__hip_bfloat16*)C)[(size_t)gr * N + gc] = __float2bfloat16(v);
                else
                    ((float*)C)[(size_t)gr * N + gc] = v;
            }
        }
    }
}

// kv^T[bh][d][e] = sum_s v[s,d]*k[s,e]  (fp32 atomics, split-S x7)
// ksum[bh][e]    = sum_s k[s,e]  via all-ones A-fragment MFMA.
// Stage k,v transposed in LDS ([row][s], stride 40 bf16) so contraction (s) is
// lane-contiguous for the MFMA fragments.
__global__ __launch_bounds__(256, 2)
void kv_mfma_kernel(const __hip_bfloat16* __restrict__ qkv,
                    float* __restrict__ kvg, float* __restrict__ ksumg)
{
    const int SPLIT = 7;
    const int bh = blockIdx.x / SPLIT;
    const int ck = blockIdx.x % SPLIT;
    const int b = bh / 12, h = bh % 12;

    __shared__ __align__(16) __hip_bfloat16 kT[64 * 40];   // [e][s0..31], stride 40
    __shared__ __align__(16) __hip_bfloat16 vT[64 * 40];   // [d][s0..31]

    const int tid = threadIdx.x;
    const int w = tid >> 6, l = tid & 63;
    const int l15 = l & 15, lq = l >> 4;

    const int half = tid >> 7;        // 0 -> stage k, 1 -> stage v
    const int idx  = tid & 127;
    const int e0 = (idx >> 4) * 8;    // 0..56, its 8 columns
    const int sp = idx & 15;          // s-pair, covers s = 2sp, 2sp+1

    const size_t rowbase = (size_t)b * 3136 * 2304 + (half ? 1536 : 768) + h * 64 + e0;
    __hip_bfloat16* Tdst = half ? vT : kT;

    f32x4 acc[4] = {};
    f32x4 accks = {};

    bf16x8 ones;
    #pragma unroll
    for (int i = 0; i < 8; ++i) ones[i] = (short)0x3F80;   // bf16 1.0

    const int s_begin = ck * 448;
    for (int s0 = s_begin; s0 < s_begin + 448; s0 += 32) {
        __syncthreads();
        bf16x8 r0 = *(const bf16x8*)(qkv + rowbase + (size_t)(s0 + 2 * sp) * 2304);
        bf16x8 r1 = *(const bf16x8*)(qkv + rowbase + (size_t)(s0 + 2 * sp + 1) * 2304);
        #pragma unroll
        for (int q = 0; q < 8; ++q) {
            unsigned pk = ((unsigned)(unsigned short)r0[q]) |
                          (((unsigned)(unsigned short)r1[q]) << 16);
            *(unsigned*)(Tdst + (e0 + q) * 40 + 2 * sp) = pk;
        }
        __syncthreads();
        // wave w: m-tile w of kv^T (16 d-rows), n-tiles 0..3 (e)
        bf16x8 a = *(const bf16x8*)(vT + (w * 16 + l15) * 40 + lq * 8);
        bf16x8 bfr[4];
        #pragma unroll
        for (int j = 0; j < 4; ++j)
            bfr[j] = *(const bf16x8*)(kT + (j * 16 + l15) * 40 + lq * 8);
        #pragma unroll
        for (int j = 0; j < 4; ++j)
            acc[j] = __builtin_amdgcn_mfma_f32_16x16x32_bf16(a, bfr[j], acc[j], 0, 0, 0);
        accks = __builtin_amdgcn_mfma_f32_16x16x32_bf16(ones, bfr[w], accks, 0, 0, 0);
    }

    float* kvdst = kvg + ((size_t)bh << 12);
    #pragma unroll
    for (int j = 0; j < 4; ++j) {
        const int col = j * 16 + l15;
        #pragma unroll
        for (int r = 0; r < 4; ++r) {
            const int row = w * 16 + lq * 4 + r;
            atomicAdd(kvdst + row * 64 + col, acc[j][r]);
        }
    }
    if (lq == 0)
        atomicAdd(ksumg + (bh << 6) + w * 16 + l15, accks[0]);
}

// att[m, h*64+d] = (q[m,:] @ kv^T[d,:]) * 1/(q[m,:].ksum + eps)
// One block per (b,h,64-row tile): 64x64x64 MFMA GEMM.
__global__ __launch_bounds__(256, 2)
void attn_mfma_kernel(const __hip_bfloat16* __restrict__ qkv,
                      const float* __restrict__ kvg,
                      const float* __restrict__ ksumg,
                      __hip_bfloat16* __restrict__ att)
{
    const int bh = blockIdx.x / 49;
    const int mt = blockIdx.x % 49;
    const int b = bh / 12, h = bh % 12;

    __shared__ __align__(16) __hip_bfloat16 qs[64 * 72];    // [m][e], stride 72
    __shared__ __align__(16) __hip_bfloat16 kvs[64 * 72];   // [d][e], stride 72
    __shared__ float kss[64];
    __shared__ float zrec[64];

    const int tid = threadIdx.x;
    const int w = tid >> 6, l = tid & 63;
    const int l15 = l & 15, lq = l >> 4;

    const size_t m0 = (size_t)b * 3136 + (size_t)mt * 64;

    {
        const int r = tid >> 2, c0 = (tid & 3) * 16;
        const __hip_bfloat16* src = qkv + (m0 + r) * 2304 + h * 64 + c0;
        bf16x8 t0 = *(const bf16x8*)(src);
        bf16x8 t1 = *(const bf16x8*)(src + 8);
        *(bf16x8*)(qs + r * 72 + c0) = t0;
        *(bf16x8*)(qs + r * 72 + c0 + 8) = t1;

        const float* kvsrc = kvg + ((size_t)bh << 12) + r * 64 + c0;
        float4 f0 = *(const float4*)(kvsrc);
        float4 f1 = *(const float4*)(kvsrc + 4);
        float4 f2 = *(const float4*)(kvsrc + 8);
        float4 f3 = *(const float4*)(kvsrc + 12);
        union { bf16x8 v; __hip_bfloat16 h[8]; } p0, p1;
        p0.h[0] = __float2bfloat16(f0.x); p0.h[1] = __float2bfloat16(f0.y);
        p0.h[2] = __float2bfloat16(f0.z); p0.h[3] = __float2bfloat16(f0.w);
        p0.h[4] = __float2bfloat16(f1.x); p0.h[5] = __float2bfloat16(f1.y);
        p0.h[6] = __float2bfloat16(f1.z); p0.h[7] = __float2bfloat16(f1.w);
        p1.h[0] = __float2bfloat16(f2.x); p1.h[1] = __float2bfloat16(f2.y);
        p1.h[2] = __float2bfloat16(f2.z); p1.h[3] = __float2bfloat16(f2.w);
        p1.h[4] = __float2bfloat16(f3.x); p1.h[5] = __float2bfloat16(f3.y);
        p1.h[6] = __float2bfloat16(f3.z); p1.h[7] = __float2bfloat16(f3.w);
        *(bf16x8*)(kvs + r * 72 + c0) = p0.v;
        *(bf16x8*)(kvs + r * 72 + c0 + 8) = p1.v;

        if (tid < 64) kss[tid] = ksumg[(bh << 6) + tid];
    }
    __syncthreads();

    if (tid < 64) {
        float zd = EPS_Z;
        #pragma unroll
        for (int c = 0; c < 8; ++c) {
            bf16x8 qv = *(const bf16x8*)(qs + tid * 72 + c * 8);
            #pragma unroll
            for (int j2 = 0; j2 < 8; ++j2) zd += b2f(qv[j2]) * kss[c * 8 + j2];
        }
        zrec[tid] = 1.0f / zd;
    }

    f32x4 acc[4] = {};
    #pragma unroll
    for (int ks = 0; ks < 2; ++ks) {
        bf16x8 a = *(const bf16x8*)(qs + (w * 16 + l15) * 72 + ks * 32 + lq * 8);
        #pragma unroll
        for (int j = 0; j < 4; ++j) {
            bf16x8 bb = *(const bf16x8*)(kvs + (j * 16 + l15) * 72 + ks * 32 + lq * 8);
            acc[j] = __builtin_amdgcn_mfma_f32_16x16x32_bf16(a, bb, acc[j], 0, 0, 0);
        }
    }
    __syncthreads();   // zrec visible to all

    #pragma unroll
    for (int j = 0; j < 4; ++j) {
        const int col = j * 16 + l15;
        #pragma unroll
        for (int r = 0; r < 4; ++r) {
            const int row = w * 16 + lq * 4 + r;
            const float v = acc[j][r] * zrec[row];
            att[(m0 + row) * 768 + h * 64 + col] = __float2bfloat16(v);
        }
    }
}

extern "C" void kernel_launch(void* const* d_in, const int* in_sizes, int n_in,
                              void* d_out, int out_size, void* d_ws, size_t ws_size,
                              hipStream_t stream)
{
    const float* x      = (const float*)d_in[0];   // [25088, 768]
    const float* W_qkv  = (const float*)d_in[1];   // [2304, 768]
    const float* W_proj = (const float*)d_in[2];   // [768, 768]
    const float* b_proj = (const float*)d_in[3];   // [768]
    float* out = (float*)d_out;

    const int M = 25088, K = 768, N1 = 2304, N2 = 768;

    __hip_bfloat16* qkv = (__hip_bfloat16*)d_ws;            // M*N1
    __hip_bfloat16* xb  = qkv + (size_t)M * N1;             // M*K
    __hip_bfloat16* wqb = xb + (size_t)M * K;               // N1*K
    __hip_bfloat16* wpb = wqb + (size_t)N1 * K;             // N2*K
    float* kvg  = (float*)(wpb + (size_t)N2 * K);           // 96*4096 fp32 (kv^T [bh][d][e])
    float* ksum = kvg + 96 * 4096;                          // 96*64 fp32
    __hip_bfloat16* att = xb;                               // alias: M*N2 <= M*K

    hipMemsetAsync(kvg, 0, (size_t)(96 * 4096 + 96 * 64) * sizeof(float), stream);

    cvt_f32_bf16<<<(M * K / 4 + 255) / 256, 256, 0, stream>>>(x, xb, M * K / 4);
    cvt_f32_bf16<<<(N1 * K / 4 + 255) / 256, 256, 0, stream>>>(W_qkv, wqb, N1 * K / 4);
    cvt_f32_bf16<<<(N2 * K / 4 + 255) / 256, 256, 0, stream>>>(W_proj, wpb, N2 * K / 4);

    gemm_bt<1, __hip_bfloat16><<<dim3(M / 128, N1 / 128), 256, 0, stream>>>(xb, wqb, qkv, nullptr, K, N1);
    kv_mfma_kernel<<<96 * 7, 256, 0, stream>>>(qkv, kvg, ksum);
    attn_mfma_kernel<<<96 * 49, 256, 0, stream>>>(qkv, kvg, ksum, att);
    gemm_bt<2, float><<<dim3(M / 128, N2 / 128), 256, 0, stream>>>(att, wpb, out, b_proj, K, N2);
}

// Round 4
// 358.265 us; speedup vs baseline: 1.5455x; 1.0665x over previous
//
#include <hip/hip_runtime.h>
#include <hip/hip_bf16.h>

#define EPS_Z 1e-4f

typedef __attribute__((ext_vector_type(8))) short bf16x8;
typedef __attribute__((ext_vector_type(4))) float f32x4;

__device__ __forceinline__ float b2f(short s) {
    union { unsigned u; float f; } cv;
    cv.u = ((unsigned)(unsigned short)s) << 16;
    return cv.f;
}

__device__ __forceinline__ void gld_lds16(const __hip_bfloat16* g, __hip_bfloat16* l) {
    __builtin_amdgcn_global_load_lds(
        (__attribute__((address_space(1))) void*)(g),
        (__attribute__((address_space(3))) void*)(l),
        16, 0, 0);
}

// fp32 -> bf16 (RNE), 4 elems/thread
__global__ __launch_bounds__(256)
void cvt_f32_bf16(const float* __restrict__ in, __hip_bfloat16* __restrict__ out, int n4)
{
    int i = blockIdx.x * 256 + threadIdx.x;
    if (i >= n4) return;
    float4 v = ((const float4*)in)[i];
    union { short4 s; __hip_bfloat16 h[4]; } o;
    o.h[0] = __float2bfloat16(v.x);
    o.h[1] = __float2bfloat16(v.y);
    o.h[2] = __float2bfloat16(v.z);
    o.h[3] = __float2bfloat16(v.w);
    ((short4*)out)[i] = o.s;
}

// C[M,N] = A[M,K] @ B[N,K]^T ; A,B bf16, fp32 accumulate.
// Grid: x = column-block (fastest -> shares A-tile, streams L2-resident B), y = row-block.
// LDS layout XOR-swizzled: chunk lane l stages global k-block ((l&7)^(l>>3)); since
// row%8 == l15%8 for all fragment rows, read column = kb ^ (l15&7) -> 2-way banks (free).
// MODE 1: relu on cols < 1536 (q,k of qkv), C bf16. MODE 2: += fp32 bias, C fp32.
template<int MODE, typename CT>
__global__ __launch_bounds__(256, 2)
void gemm_bt(const __hip_bfloat16* __restrict__ A,
             const __hip_bfloat16* __restrict__ B,
             CT* __restrict__ C,
             const float* __restrict__ bias,
             int K, int N)
{
    __shared__ __align__(16) __hip_bfloat16 As[128 * 64];
    __shared__ __align__(16) __hip_bfloat16 Bs[128 * 64];
    const int tid = threadIdx.x;
    const int w = tid >> 6;
    const int l = tid & 63;
    const int wr = (w >> 1) * 64;
    const int wc = (w & 1) * 64;
    const int l15 = l & 15;
    const int lq = l >> 4;
    const int rx = l15 & 7;             // row %8 of every fragment row this lane touches

    f32x4 acc[4][4] = {};

    const int srow8 = l >> 3;                       // row within 8-row chunk
    const int scol = (((l & 7) ^ (l >> 3)) << 3);   // XOR-swizzled k-block source

    const __hip_bfloat16* Ab = A + (size_t)blockIdx.y * 128 * K;
    const __hip_bfloat16* Bb = B + (size_t)blockIdx.x * 128 * K;

    for (int k0 = 0; k0 < K; k0 += 64) {
        __syncthreads();
        #pragma unroll
        for (int i = 0; i < 4; ++i) {
            const int chunk = w * 4 + i;            // 16 chunks of 1024B per tile
            const int row = chunk * 8 + srow8;      // 0..127
            gld_lds16(Ab + (size_t)row * K + (k0 + scol), As + chunk * 512);
            gld_lds16(Bb + (size_t)row * K + (k0 + scol), Bs + chunk * 512);
        }
        __syncthreads();
        #pragma unroll
        for (int kk = 0; kk < 64; kk += 32) {
            const int kb = (kk >> 3) + lq;
            const int col = (kb ^ rx) << 3;
            bf16x8 a[4], b[4];
            #pragma unroll
            for (int i = 0; i < 4; ++i)
                a[i] = *(const bf16x8*)(As + (wr + i * 16 + l15) * 64 + col);
            #pragma unroll
            for (int j = 0; j < 4; ++j)
                b[j] = *(const bf16x8*)(Bs + (wc + j * 16 + l15) * 64 + col);
            #pragma unroll
            for (int i = 0; i < 4; ++i)
                #pragma unroll
                for (int j = 0; j < 4; ++j)
                    acc[i][j] = __builtin_amdgcn_mfma_f32_16x16x32_bf16(a[i], b[j], acc[i][j], 0, 0, 0);
        }
    }

    // C/D layout: col = lane&15, row = (lane>>4)*4 + r  [m89/m91 verified]
    const int crow0 = blockIdx.y * 128 + wr + lq * 4;
    const int ccol0 = blockIdx.x * 128 + wc + l15;
    #pragma unroll
    for (int i = 0; i < 4; ++i) {
        #pragma unroll
        for (int j = 0; j < 4; ++j) {
            const int gc = ccol0 + j * 16;
            const float badd = (MODE == 2) ? bias[gc] : 0.0f;
            #pragma unroll
            for (int r = 0; r < 4; ++r) {
                const int gr = crow0 + i * 16 + r;
                float v = acc[i][j][r];
                if (MODE == 1 && gc < 1536) v = fmaxf(v, 0.0f);
                if (MODE == 2) v += badd;
                if (MODE == 1)
                    ((__hip_bfloat16*)C)[(size_t)gr * N + gc] = __float2bfloat16(v);
                else
                    ((float*)C)[(size_t)gr * N + gc] = v;
            }
        }
    }
}

// kv^T[bh][d][e] = sum_s v[s,d]*k[s,e]  (fp32 atomics, split-S x7)
// ksum[bh][e]    = sum_s k[s,e]  via all-ones A-fragment MFMA.
__global__ __launch_bounds__(256, 2)
void kv_mfma_kernel(const __hip_bfloat16* __restrict__ qkv,
                    float* __restrict__ kvg, float* __restrict__ ksumg)
{
    const int SPLIT = 7;
    const int bh = blockIdx.x / SPLIT;
    const int ck = blockIdx.x % SPLIT;
    const int b = bh / 12, h = bh % 12;

    __shared__ __align__(16) __hip_bfloat16 kT[64 * 40];   // [e][s0..31], stride 40
    __shared__ __align__(16) __hip_bfloat16 vT[64 * 40];   // [d][s0..31]

    const int tid = threadIdx.x;
    const int w = tid >> 6, l = tid & 63;
    const int l15 = l & 15, lq = l >> 4;

    const int half = tid >> 7;        // 0 -> stage k, 1 -> stage v
    const int idx  = tid & 127;
    const int e0 = (idx >> 4) * 8;
    const int sp = idx & 15;

    const size_t rowbase = (size_t)b * 3136 * 2304 + (half ? 1536 : 768) + h * 64 + e0;
    __hip_bfloat16* Tdst = half ? vT : kT;

    f32x4 acc[4] = {};
    f32x4 accks = {};

    bf16x8 ones;
    #pragma unroll
    for (int i = 0; i < 8; ++i) ones[i] = (short)0x3F80;   // bf16 1.0

    const int s_begin = ck * 448;
    for (int s0 = s_begin; s0 < s_begin + 448; s0 += 32) {
        __syncthreads();
        bf16x8 r0 = *(const bf16x8*)(qkv + rowbase + (size_t)(s0 + 2 * sp) * 2304);
        bf16x8 r1 = *(const bf16x8*)(qkv + rowbase + (size_t)(s0 + 2 * sp + 1) * 2304);
        #pragma unroll
        for (int q = 0; q < 8; ++q) {
            unsigned pk = ((unsigned)(unsigned short)r0[q]) |
                          (((unsigned)(unsigned short)r1[q]) << 16);
            *(unsigned*)(Tdst + (e0 + q) * 40 + 2 * sp) = pk;
        }
        __syncthreads();
        bf16x8 a = *(const bf16x8*)(vT + (w * 16 + l15) * 40 + lq * 8);
        bf16x8 bfr[4];
        #pragma unroll
        for (int j = 0; j < 4; ++j)
            bfr[j] = *(const bf16x8*)(kT + (j * 16 + l15) * 40 + lq * 8);
        #pragma unroll
        for (int j = 0; j < 4; ++j)
            acc[j] = __builtin_amdgcn_mfma_f32_16x16x32_bf16(a, bfr[j], acc[j], 0, 0, 0);
        accks = __builtin_amdgcn_mfma_f32_16x16x32_bf16(ones, bfr[w], accks, 0, 0, 0);
    }

    float* kvdst = kvg + ((size_t)bh << 12);
    #pragma unroll
    for (int j = 0; j < 4; ++j) {
        const int col = j * 16 + l15;
        #pragma unroll
        for (int r = 0; r < 4; ++r) {
            const int row = w * 16 + lq * 4 + r;
            atomicAdd(kvdst + row * 64 + col, acc[j][r]);
        }
    }
    if (lq == 0)
        atomicAdd(ksumg + (bh << 6) + w * 16 + l15, accks[0]);
}

// att[m, h*64+d] = (q[m,:] @ kv^T[d,:]) * 1/(q[m,:].ksum + eps)
__global__ __launch_bounds__(256, 2)
void attn_mfma_kernel(const __hip_bfloat16* __restrict__ qkv,
                      const float* __restrict__ kvg,
                      const float* __restrict__ ksumg,
                      __hip_bfloat16* __restrict__ att)
{
    const int bh = blockIdx.x / 49;
    const int mt = blockIdx.x % 49;
    const int b = bh / 12, h = bh % 12;

    __shared__ __align__(16) __hip_bfloat16 qs[64 * 72];
    __shared__ __align__(16) __hip_bfloat16 kvs[64 * 72];
    __shared__ float kss[64];
    __shared__ float zrec[64];

    const int tid = threadIdx.x;
    const int w = tid >> 6, l = tid & 63;
    const int l15 = l & 15, lq = l >> 4;

    const size_t m0 = (size_t)b * 3136 + (size_t)mt * 64;

    {
        const int r = tid >> 2, c0 = (tid & 3) * 16;
        const __hip_bfloat16* src = qkv + (m0 + r) * 2304 + h * 64 + c0;
        bf16x8 t0 = *(const bf16x8*)(src);
        bf16x8 t1 = *(const bf16x8*)(src + 8);
        *(bf16x8*)(qs + r * 72 + c0) = t0;
        *(bf16x8*)(qs + r * 72 + c0 + 8) = t1;

        const float* kvsrc = kvg + ((size_t)bh << 12) + r * 64 + c0;
        float4 f0 = *(const float4*)(kvsrc);
        float4 f1 = *(const float4*)(kvsrc + 4);
        float4 f2 = *(const float4*)(kvsrc + 8);
        float4 f3 = *(const float4*)(kvsrc + 12);
        union { bf16x8 v; __hip_bfloat16 h[8]; } p0, p1;
        p0.h[0] = __float2bfloat16(f0.x); p0.h[1] = __float2bfloat16(f0.y);
        p0.h[2] = __float2bfloat16(f0.z); p0.h[3] = __float2bfloat16(f0.w);
        p0.h[4] = __float2bfloat16(f1.x); p0.h[5] = __float2bfloat16(f1.y);
        p0.h[6] = __float2bfloat16(f1.z); p0.h[7] = __float2bfloat16(f1.w);
        p1.h[0] = __float2bfloat16(f2.x); p1.h[1] = __float2bfloat16(f2.y);
        p1.h[2] = __float2bfloat16(f2.z); p1.h[3] = __float2bfloat16(f2.w);
        p1.h[4] = __float2bfloat16(f3.x); p1.h[5] = __float2bfloat16(f3.y);
        p1.h[6] = __float2bfloat16(f3.z); p1.h[7] = __float2bfloat16(f3.w);
        *(bf16x8*)(kvs + r * 72 + c0) = p0.v;
        *(bf16x8*)(kvs + r * 72 + c0 + 8) = p1.v;

        if (tid < 64) kss[tid] = ksumg[(bh << 6) + tid];
    }
    __syncthreads();

    if (tid < 64) {
        float zd = EPS_Z;
        #pragma unroll
        for (int c = 0; c < 8; ++c) {
            bf16x8 qv = *(const bf16x8*)(qs + tid * 72 + c * 8);
            #pragma unroll
            for (int j2 = 0; j2 < 8; ++j2) zd += b2f(qv[j2]) * kss[c * 8 + j2];
        }
        zrec[tid] = 1.0f / zd;
    }

    f32x4 acc[4] = {};
    #pragma unroll
    for (int ks = 0; ks < 2; ++ks) {
        bf16x8 a = *(const bf16x8*)(qs + (w * 16 + l15) * 72 + ks * 32 + lq * 8);
        #pragma unroll
        for (int j = 0; j < 4; ++j) {
            bf16x8 bb = *(const bf16x8*)(kvs + (j * 16 + l15) * 72 + ks * 32 + lq * 8);
            acc[j] = __builtin_amdgcn_mfma_f32_16x16x32_bf16(a, bb, acc[j], 0, 0, 0);
        }
    }
    __syncthreads();

    #pragma unroll
    for (int j = 0; j < 4; ++j) {
        const int col = j * 16 + l15;
        #pragma unroll
        for (int r = 0; r < 4; ++r) {
            const int row = w * 16 + lq * 4 + r;
            const float v = acc[j][r] * zrec[row];
            att[(m0 + row) * 768 + h * 64 + col] = __float2bfloat16(v);
        }
    }
}

extern "C" void kernel_launch(void* const* d_in, const int* in_sizes, int n_in,
                              void* d_out, int out_size, void* d_ws, size_t ws_size,
                              hipStream_t stream)
{
    const float* x      = (const float*)d_in[0];   // [25088, 768]
    const float* W_qkv  = (const float*)d_in[1];   // [2304, 768]
    const float* W_proj = (const float*)d_in[2];   // [768, 768]
    const float* b_proj = (const float*)d_in[3];   // [768]
    float* out = (float*)d_out;

    const int M = 25088, K = 768, N1 = 2304, N2 = 768;

    __hip_bfloat16* qkv = (__hip_bfloat16*)d_ws;            // M*N1
    __hip_bfloat16* xb  = qkv + (size_t)M * N1;             // M*K
    __hip_bfloat16* wqb = xb + (size_t)M * K;               // N1*K
    __hip_bfloat16* wpb = wqb + (size_t)N1 * K;             // N2*K
    float* kvg  = (float*)(wpb + (size_t)N2 * K);           // 96*4096 fp32 (kv^T [bh][d][e])
    float* ksum = kvg + 96 * 4096;                          // 96*64 fp32
    __hip_bfloat16* att = xb;                               // alias: M*N2 <= M*K

    hipMemsetAsync(kvg, 0, (size_t)(96 * 4096 + 96 * 64) * sizeof(float), stream);

    cvt_f32_bf16<<<(M * K / 4 + 255) / 256, 256, 0, stream>>>(x, xb, M * K / 4);
    cvt_f32_bf16<<<(N1 * K / 4 + 255) / 256, 256, 0, stream>>>(W_qkv, wqb, N1 * K / 4);
    cvt_f32_bf16<<<(N2 * K / 4 + 255) / 256, 256, 0, stream>>>(W_proj, wpb, N2 * K / 4);

    gemm_bt<1, __hip_bfloat16><<<dim3(N1 / 128, M / 128), 256, 0, stream>>>(xb, wqb, qkv, nullptr, K, N1);
    kv_mfma_kernel<<<96 * 7, 256, 0, stream>>>(qkv, kvg, ksum);
    attn_mfma_kernel<<<96 * 49, 256, 0, stream>>>(qkv, kvg, ksum, att);
    gemm_bt<2, float><<<dim3(N2 / 128, M / 128), 256, 0, stream>>>(att, wpb, out, b_proj, K, N2);
}

// Round 5
// 345.597 us; speedup vs baseline: 1.6021x; 1.0367x over previous
//
#include <hip/hip_runtime.h>
#include <hip/hip_bf16.h>

#define EPS_Z 1e-4f

typedef __attribute__((ext_vector_type(8))) short bf16x8;
typedef __attribute__((ext_vector_type(4))) float f32x4;

__device__ __forceinline__ float b2f(short s) {
    union { unsigned u; float f; } cv;
    cv.u = ((unsigned)(unsigned short)s) << 16;
    return cv.f;
}

__device__ __forceinline__ void gld_lds16(const __hip_bfloat16* g, __hip_bfloat16* l) {
    __builtin_amdgcn_global_load_lds(
        (__attribute__((address_space(1))) void*)(g),
        (__attribute__((address_space(3))) void*)(l),
        16, 0, 0);
}

// fp32 -> bf16 (RNE), 4 elems/thread
__global__ __launch_bounds__(256)
void cvt_f32_bf16(const float* __restrict__ in, __hip_bfloat16* __restrict__ out, int n4)
{
    int i = blockIdx.x * 256 + threadIdx.x;
    if (i >= n4) return;
    float4 v = ((const float4*)in)[i];
    union { short4 s; __hip_bfloat16 h[4]; } o;
    o.h[0] = __float2bfloat16(v.x);
    o.h[1] = __float2bfloat16(v.y);
    o.h[2] = __float2bfloat16(v.z);
    o.h[3] = __float2bfloat16(v.w);
    ((short4*)out)[i] = o.s;
}

// C[M,N] = A[M,K] @ B[N,K]^T ; A,B bf16, fp32 accumulate.
// 1-D grid with XCD-contiguous remap: g' = (g&7)*(NB/8) + (g>>3); x = g'%gx fastest
// (A-tile reuse within an XCD's contiguous row-band, B streams L2-resident).
// LDS XOR-swizzled (R3): zero bank conflicts.
// MODE 1: relu on cols < 1536, C bf16. MODE 2: += fp32 bias, C fp32.
template<int MODE, typename CT>
__global__ __launch_bounds__(256, 2)
void gemm_bt(const __hip_bfloat16* __restrict__ A,
             const __hip_bfloat16* __restrict__ B,
             CT* __restrict__ C,
             const float* __restrict__ bias,
             int K, int N, int gx)
{
    __shared__ __align__(16) __hip_bfloat16 As[128 * 64];
    __shared__ __align__(16) __hip_bfloat16 Bs[128 * 64];
    const int g = blockIdx.x;
    const int gp = (g & 7) * ((int)gridDim.x >> 3) + (g >> 3);
    const int bx = gp % gx;
    const int by = gp / gx;

    const int tid = threadIdx.x;
    const int w = tid >> 6;
    const int l = tid & 63;
    const int wr = (w >> 1) * 64;
    const int wc = (w & 1) * 64;
    const int l15 = l & 15;
    const int lq = l >> 4;
    const int rx = l15 & 7;

    f32x4 acc[4][4] = {};

    const int srow8 = l >> 3;
    const int scol = (((l & 7) ^ (l >> 3)) << 3);

    const __hip_bfloat16* Ab = A + (size_t)by * 128 * K;
    const __hip_bfloat16* Bb = B + (size_t)bx * 128 * K;

    for (int k0 = 0; k0 < K; k0 += 64) {
        __syncthreads();
        #pragma unroll
        for (int i = 0; i < 4; ++i) {
            const int chunk = w * 4 + i;
            const int row = chunk * 8 + srow8;
            gld_lds16(Ab + (size_t)row * K + (k0 + scol), As + chunk * 512);
            gld_lds16(Bb + (size_t)row * K + (k0 + scol), Bs + chunk * 512);
        }
        __syncthreads();
        #pragma unroll
        for (int kk = 0; kk < 64; kk += 32) {
            const int kb = (kk >> 3) + lq;
            const int col = (kb ^ rx) << 3;
            bf16x8 a[4], b[4];
            #pragma unroll
            for (int i = 0; i < 4; ++i)
                a[i] = *(const bf16x8*)(As + (wr + i * 16 + l15) * 64 + col);
            #pragma unroll
            for (int j = 0; j < 4; ++j)
                b[j] = *(const bf16x8*)(Bs + (wc + j * 16 + l15) * 64 + col);
            #pragma unroll
            for (int i = 0; i < 4; ++i)
                #pragma unroll
                for (int j = 0; j < 4; ++j)
                    acc[i][j] = __builtin_amdgcn_mfma_f32_16x16x32_bf16(a[i], b[j], acc[i][j], 0, 0, 0);
        }
    }

    const int crow0 = by * 128 + wr + lq * 4;
    const int ccol0 = bx * 128 + wc + l15;
    #pragma unroll
    for (int i = 0; i < 4; ++i) {
        #pragma unroll
        for (int j = 0; j < 4; ++j) {
            const int gc = ccol0 + j * 16;
            const float badd = (MODE == 2) ? bias[gc] : 0.0f;
            #pragma unroll
            for (int r = 0; r < 4; ++r) {
                const int gr = crow0 + i * 16 + r;
                float v = acc[i][j][r];
                if (MODE == 1 && gc < 1536) v = fmaxf(v, 0.0f);
                if (MODE == 2) v += badd;
                if (MODE == 1)
                    ((__hip_bfloat16*)C)[(size_t)gr * N + gc] = __float2bfloat16(v);
                else
                    ((float*)C)[(size_t)gr * N + gc] = v;
            }
        }
    }
}

// kv^T[bh][d][e] = sum_s v[s,d]*k[s,e]  (fp32 atomics, split-S x14)
// ksum[bh][e]    = sum_s k[s,e]  via all-ones A-fragment MFMA.
__global__ __launch_bounds__(256)
void kv_mfma_kernel(const __hip_bfloat16* __restrict__ qkv,
                    float* __restrict__ kvg, float* __restrict__ ksumg)
{
    const int SPLIT = 14;
    const int bh = blockIdx.x / SPLIT;
    const int ck = blockIdx.x % SPLIT;
    const int b = bh / 12, h = bh % 12;

    __shared__ __align__(16) __hip_bfloat16 kT[64 * 40];   // [e][s0..31], stride 40
    __shared__ __align__(16) __hip_bfloat16 vT[64 * 40];   // [d][s0..31]

    const int tid = threadIdx.x;
    const int w = tid >> 6, l = tid & 63;
    const int l15 = l & 15, lq = l >> 4;

    const int half = tid >> 7;        // 0 -> stage k, 1 -> stage v
    const int idx  = tid & 127;
    const int e0 = (idx >> 4) * 8;
    const int sp = idx & 15;

    const size_t rowbase = (size_t)b * 3136 * 2304 + (half ? 1536 : 768) + h * 64 + e0;
    __hip_bfloat16* Tdst = half ? vT : kT;

    f32x4 acc[4] = {};
    f32x4 accks = {};

    bf16x8 ones;
    #pragma unroll
    for (int i = 0; i < 8; ++i) ones[i] = (short)0x3F80;   // bf16 1.0

    const int s_begin = ck * 224;
    for (int s0 = s_begin; s0 < s_begin + 224; s0 += 32) {
        __syncthreads();
        bf16x8 r0 = *(const bf16x8*)(qkv + rowbase + (size_t)(s0 + 2 * sp) * 2304);
        bf16x8 r1 = *(const bf16x8*)(qkv + rowbase + (size_t)(s0 + 2 * sp + 1) * 2304);
        #pragma unroll
        for (int q = 0; q < 8; ++q) {
            unsigned pk = ((unsigned)(unsigned short)r0[q]) |
                          (((unsigned)(unsigned short)r1[q]) << 16);
            *(unsigned*)(Tdst + (e0 + q) * 40 + 2 * sp) = pk;
        }
        __syncthreads();
        bf16x8 a = *(const bf16x8*)(vT + (w * 16 + l15) * 40 + lq * 8);
        bf16x8 bfr[4];
        #pragma unroll
        for (int j = 0; j < 4; ++j)
            bfr[j] = *(const bf16x8*)(kT + (j * 16 + l15) * 40 + lq * 8);
        #pragma unroll
        for (int j = 0; j < 4; ++j)
            acc[j] = __builtin_amdgcn_mfma_f32_16x16x32_bf16(a, bfr[j], acc[j], 0, 0, 0);
        accks = __builtin_amdgcn_mfma_f32_16x16x32_bf16(ones, bfr[w], accks, 0, 0, 0);
    }

    float* kvdst = kvg + ((size_t)bh << 12);
    #pragma unroll
    for (int j = 0; j < 4; ++j) {
        const int col = j * 16 + l15;
        #pragma unroll
        for (int r = 0; r < 4; ++r) {
            const int row = w * 16 + lq * 4 + r;
            atomicAdd(kvdst + row * 64 + col, acc[j][r]);
        }
    }
    if (lq == 0)
        atomicAdd(ksumg + (bh << 6) + w * 16 + l15, accks[0]);
}

// att[m, h*64+d] = (q[m,:] @ kv^T[d,:]) * 1/(q[m,:].ksum + eps)
// LDS-free, barrier-free: one wave per (bh, 16-row tile). q loads land directly in
// MFMA A-fragment layout; kvb (bf16) loads land directly in B-fragment layout.
__global__ __launch_bounds__(256)
void attn_mfma2(const __hip_bfloat16* __restrict__ qkv,
                const __hip_bfloat16* __restrict__ kvb,
                const float* __restrict__ ksumg,
                __hip_bfloat16* __restrict__ att)
{
    const int bh = blockIdx.x / 49;
    const int mt = blockIdx.x % 49;
    const int b = bh / 12, h = bh % 12;
    const int tid = threadIdx.x;
    const int w = tid >> 6, l = tid & 63;
    const int l15 = l & 15, lq = l >> 4;

    const size_t m0 = (size_t)b * 3136 + (size_t)mt * 64 + w * 16;

    // A-fragments: q[row=l15][e = ks*32 + lq*8 + j]
    const __hip_bfloat16* qrow = qkv + (m0 + l15) * 2304 + h * 64;
    bf16x8 aq0 = *(const bf16x8*)(qrow + lq * 8);
    bf16x8 aq1 = *(const bf16x8*)(qrow + 32 + lq * 8);

    // z: per-lane partial over its 16 e-values, then butterfly over the 4 lanes/row
    const float* ks = ksumg + (bh << 6);
    float kse[8], kse1[8];
    *(float4*)(kse)      = *(const float4*)(ks + lq * 8);
    *(float4*)(kse + 4)  = *(const float4*)(ks + lq * 8 + 4);
    *(float4*)(kse1)     = *(const float4*)(ks + 32 + lq * 8);
    *(float4*)(kse1 + 4) = *(const float4*)(ks + 32 + lq * 8 + 4);
    float zp = 0.0f;
    #pragma unroll
    for (int j = 0; j < 8; ++j)
        zp += b2f(aq0[j]) * kse[j] + b2f(aq1[j]) * kse1[j];
    zp += __shfl_xor(zp, 16);
    zp += __shfl_xor(zp, 32);
    const float zr = 1.0f / (zp + EPS_Z);   // lane i<16 holds z-recip for row i

    // B-fragments from kvb[bh][d][e] (row-major, stride 64)
    const __hip_bfloat16* kvh = kvb + ((size_t)bh << 12);
    f32x4 acc[4] = {};
    #pragma unroll
    for (int j = 0; j < 4; ++j) {
        bf16x8 b0 = *(const bf16x8*)(kvh + (j * 16 + l15) * 64 + lq * 8);
        bf16x8 b1 = *(const bf16x8*)(kvh + (j * 16 + l15) * 64 + 32 + lq * 8);
        acc[j] = __builtin_amdgcn_mfma_f32_16x16x32_bf16(aq0, b0, acc[j], 0, 0, 0);
        acc[j] = __builtin_amdgcn_mfma_f32_16x16x32_bf16(aq1, b1, acc[j], 0, 0, 0);
    }

    float zrow[4];
    #pragma unroll
    for (int r = 0; r < 4; ++r) zrow[r] = __shfl(zr, lq * 4 + r);

    #pragma unroll
    for (int j = 0; j < 4; ++j) {
        const int col = j * 16 + l15;
        #pragma unroll
        for (int r = 0; r < 4; ++r) {
            const int row = lq * 4 + r;
            att[(m0 + row) * 768 + h * 64 + col] = __float2bfloat16(acc[j][r] * zrow[r]);
        }
    }
}

extern "C" void kernel_launch(void* const* d_in, const int* in_sizes, int n_in,
                              void* d_out, int out_size, void* d_ws, size_t ws_size,
                              hipStream_t stream)
{
    const float* x      = (const float*)d_in[0];   // [25088, 768]
    const float* W_qkv  = (const float*)d_in[1];   // [2304, 768]
    const float* W_proj = (const float*)d_in[2];   // [768, 768]
    const float* b_proj = (const float*)d_in[3];   // [768]
    float* out = (float*)d_out;

    const int M = 25088, K = 768, N1 = 2304, N2 = 768;

    __hip_bfloat16* qkv = (__hip_bfloat16*)d_ws;            // M*N1
    __hip_bfloat16* xb  = qkv + (size_t)M * N1;             // M*K
    __hip_bfloat16* wqb = xb + (size_t)M * K;               // N1*K
    __hip_bfloat16* wpb = wqb + (size_t)N1 * K;             // N2*K
    float* kvg  = (float*)(wpb + (size_t)N2 * K);           // 96*4096 fp32 (kv^T [bh][d][e])
    float* ksum = kvg + 96 * 4096;                          // 96*64 fp32
    __hip_bfloat16* kvb = (__hip_bfloat16*)(ksum + 96 * 64);// 96*4096 bf16
    __hip_bfloat16* att = xb;                               // alias: M*N2 <= M*K

    hipMemsetAsync(kvg, 0, (size_t)(96 * 4096 + 96 * 64) * sizeof(float), stream);

    cvt_f32_bf16<<<(M * K / 4 + 255) / 256, 256, 0, stream>>>(x, xb, M * K / 4);
    cvt_f32_bf16<<<(N1 * K / 4 + 255) / 256, 256, 0, stream>>>(W_qkv, wqb, N1 * K / 4);
    cvt_f32_bf16<<<(N2 * K / 4 + 255) / 256, 256, 0, stream>>>(W_proj, wpb, N2 * K / 4);

    gemm_bt<1, __hip_bfloat16><<<(M / 128) * (N1 / 128), 256, 0, stream>>>(
        xb, wqb, qkv, nullptr, K, N1, N1 / 128);
    kv_mfma_kernel<<<96 * 14, 256, 0, stream>>>(qkv, kvg, ksum);
    cvt_f32_bf16<<<(96 * 4096 / 4 + 255) / 256, 256, 0, stream>>>(kvg, kvb, 96 * 4096 / 4);
    attn_mfma2<<<96 * 49, 256, 0, stream>>>(qkv, kvb, ksum, att);
    gemm_bt<2, float><<<(M / 128) * (N2 / 128), 256, 0, stream>>>(
        att, wpb, out, b_proj, K, N2, N2 / 128);
}